// Round 11
// baseline (322.517 us; speedup 1.0000x reference)
//
#include <hip/hip_runtime.h>

// Affine_Linear_Abla_Quat — v8: producer/consumer wave specialization.
// 256 blocks (1/CU), 512 thr: waves 0-3 produce (load X/J, quat->terms->LDS),
// waves 4-7 consume (MFMA GEMM vs W, store Y). TT double-buffered (147 KB).
// Rationale: compiler provably strips intra-wave pipelining (v3/v7 VGPR=52);
// heterogeneous waves per SIMD overlap HBM latency with MFMA/LDS work at the
// hardware scheduler level. No cross-MFMA-loop register payloads (v4/v6 spill
// lesson): producers have no MFMA loop; consumers only carry the accumulator.

typedef __bf16 bf16_t;
typedef __attribute__((ext_vector_type(8))) __bf16 bf16x8;
typedef __attribute__((ext_vector_type(4))) __bf16 bf16x4;
typedef __attribute__((ext_vector_type(4))) float f32x4;

constexpr int Dd  = 256;   // D == F
constexpr int Gp  = 16;    // pairs per chunk -> M = 48
constexpr int NCH = 8;     // chunks per block
constexpr int TPB = 512;   // 8 waves: 4 producer + 4 consumer

__device__ __forceinline__ bf16_t to_bf16(float f) {
    unsigned u = __builtin_bit_cast(unsigned, f);
    u += 0x7FFFu + ((u >> 16) & 1u);          // RNE
    unsigned short h = (unsigned short)(u >> 16);
    return __builtin_bit_cast(bf16_t, h);
}

// swizzled element index into a TT buffer: row-major [48][768], 16B granule XOR (row&7)
__device__ __forceinline__ int swz(int row, int k) {
    return row * 768 + (k ^ ((row & 7) << 3));
}

// ---- prologue: A,B,C (f32 256x256) -> W bf16 [3][256][256] in d_ws ----
__global__ __launch_bounds__(256)
void convert_w_kernel(const float* __restrict__ A, const float* __restrict__ B,
                      const float* __restrict__ C, bf16_t* __restrict__ W)
{
    const int e4 = (blockIdx.x * 256 + threadIdx.x) * 4;
    const float* src;
    if (e4 < 65536)        src = A + e4;
    else if (e4 < 131072)  src = B + (e4 - 65536);
    else                   src = C + (e4 - 131072);
    const float4 v = *reinterpret_cast<const float4*>(src);
    bf16x4 o;
    o[0] = to_bf16(v.x); o[1] = to_bf16(v.y); o[2] = to_bf16(v.z); o[3] = to_bf16(v.w);
    *reinterpret_cast<bf16x4*>(W + e4) = o;
}

// ------------------------------ main kernel ------------------------------
__global__ __launch_bounds__(TPB, 2)
void alaq_pc_kernel(const float* __restrict__ X, const float* __restrict__ J,
                    const bf16_t* __restrict__ W, float* __restrict__ Y)
{
    __shared__ bf16_t TT[2][48 * 768];   // 147,456 B -> 1 block/CU

    const int tid = threadIdx.x;
    const int w   = tid >> 6;
    const int l   = tid & 63;
    const long pair0 = (long)blockIdx.x * (Gp * NCH);

    // ---------------- producer: fill TT[chunk&1] for `chunk` ----------------
    auto PRODUCE = [&](int chunk) {
        bf16_t* tt = TT[chunk & 1];
        const long eb = (pair0 + (long)chunk * Gp) * Dd;
        // 256 producer threads, 4096 elements: iter `it` = pair it, e = tid
        #pragma unroll
        for (int g = 0; g < 2; ++g) {          // two batches of 8 pairs
            float4 qv[8];
            float  xv[8][3];
            #pragma unroll
            for (int j = 0; j < 8; ++j) {
                const long base = eb + (g * 8 + j) * 256 + tid;
                qv[j] = *reinterpret_cast<const float4*>(J + base * 4);
                const float* xp = X + base * 3;
                xv[j][0] = xp[0]; xv[j][1] = xp[1]; xv[j][2] = xp[2];
            }
            #pragma unroll
            for (int j = 0; j < 8; ++j) {
                const int p = g * 8 + j;       // pair in chunk
                const int e = tid;             // 0..255
                const float4 q = qv[j];
                const float x0 = xv[j][0], x1 = xv[j][1], x2 = xv[j][2];

                const float nsq = q.x*q.x + q.y*q.y + q.z*q.z + q.w*q.w;
                const float inv = 1.0f / fmaxf(sqrtf(nsq), 1e-12f);
                const float qx = q.x*inv, qy = q.y*inv, qz = q.z*inv, qw = q.w*inv;
                const float s = 2.0f / (qw*qw + qx*qx + qy*qy + qz*qz);

                const float r00 = 1.0f - s*(qy*qy + qz*qz);
                const float r01 = s*(qx*qy - qz*qw);
                const float r02 = s*(qx*qz + qy*qw);
                const float r10 = s*(qx*qy + qz*qw);
                const float r11 = 1.0f - s*(qx*qx + qz*qz);
                const float r12 = s*(qy*qz - qx*qw);
                const float r20 = s*(qx*qz - qy*qw);
                const float r21 = s*(qy*qz + qx*qw);
                const float r22 = 1.0f - s*(qx*qx + qy*qy);

                const float rt0 = r00*x0 + r10*x1 + r20*x2;
                const float rt1 = r01*x0 + r11*x1 + r21*x2;
                const float rt2 = r02*x0 + r12*x1 + r22*x2;

                const int row = p * 3;
                tt[swz(row    ,       e)] = to_bf16(r00*rt0 + r01*rt1);
                tt[swz(row + 1,       e)] = to_bf16(r10*rt0 + r11*rt1);
                tt[swz(row + 2,       e)] = to_bf16(r20*rt0 + r21*rt1);
                tt[swz(row    , 256 + e)] = to_bf16(r01*rt0 - r00*rt1);
                tt[swz(row + 1, 256 + e)] = to_bf16(r11*rt0 - r10*rt1);
                tt[swz(row + 2, 256 + e)] = to_bf16(r21*rt0 - r20*rt1);
                tt[swz(row    , 512 + e)] = to_bf16(r02*rt2);
                tt[swz(row + 1, 512 + e)] = to_bf16(r12*rt2);
                tt[swz(row + 2, 512 + e)] = to_bf16(r22*rt2);
            }
        }
    };

    // ---------------- consumer: GEMM chunk from TT[chunk&1], store Y ----------------
    const int wc = (w >= 4) ? (w - 4) : 0;   // consumer wave 0..3
    const int lr = l & 15;
    const int lq = l >> 4;
    const bf16_t* Wb = W + ((4 * wc) * 16 + lr) * 256 + (lq << 3);  // ni stride 16*256
    const int swzmask = (lr & 7) << 3;

    auto CONSUME = [&](int chunk) {
        const bf16_t* tt = TT[chunk & 1];
        f32x4 acc[3][4] = {};

        #pragma unroll
        for (int k0 = 0; k0 < 24; ++k0) {
            const int term = k0 >> 3;
            const int ebo  = (k0 & 7) << 5;
            const bf16x8 b0 = *reinterpret_cast<const bf16x8*>(Wb                + (term << 16) + ebo);
            const bf16x8 b1 = *reinterpret_cast<const bf16x8*>(Wb + 1 * 16 * 256 + (term << 16) + ebo);
            const bf16x8 b2 = *reinterpret_cast<const bf16x8*>(Wb + 2 * 16 * 256 + (term << 16) + ebo);
            const bf16x8 b3 = *reinterpret_cast<const bf16x8*>(Wb + 3 * 16 * 256 + (term << 16) + ebo);

            const int kswz = (((k0 << 5) + (lq << 3)) ^ swzmask);
            const bf16x8 a0 = *reinterpret_cast<const bf16x8*>(&tt[      lr  * 768 + kswz]);
            const bf16x8 a1 = *reinterpret_cast<const bf16x8*>(&tt[(16 + lr) * 768 + kswz]);
            const bf16x8 a2 = *reinterpret_cast<const bf16x8*>(&tt[(32 + lr) * 768 + kswz]);

            acc[0][0] = __builtin_amdgcn_mfma_f32_16x16x32_bf16(a0, b0, acc[0][0], 0, 0, 0);
            acc[1][0] = __builtin_amdgcn_mfma_f32_16x16x32_bf16(a1, b0, acc[1][0], 0, 0, 0);
            acc[2][0] = __builtin_amdgcn_mfma_f32_16x16x32_bf16(a2, b0, acc[2][0], 0, 0, 0);
            acc[0][1] = __builtin_amdgcn_mfma_f32_16x16x32_bf16(a0, b1, acc[0][1], 0, 0, 0);
            acc[1][1] = __builtin_amdgcn_mfma_f32_16x16x32_bf16(a1, b1, acc[1][1], 0, 0, 0);
            acc[2][1] = __builtin_amdgcn_mfma_f32_16x16x32_bf16(a2, b1, acc[2][1], 0, 0, 0);
            acc[0][2] = __builtin_amdgcn_mfma_f32_16x16x32_bf16(a0, b2, acc[0][2], 0, 0, 0);
            acc[1][2] = __builtin_amdgcn_mfma_f32_16x16x32_bf16(a1, b2, acc[1][2], 0, 0, 0);
            acc[2][2] = __builtin_amdgcn_mfma_f32_16x16x32_bf16(a2, b2, acc[2][2], 0, 0, 0);
            acc[0][3] = __builtin_amdgcn_mfma_f32_16x16x32_bf16(a0, b3, acc[0][3], 0, 0, 0);
            acc[1][3] = __builtin_amdgcn_mfma_f32_16x16x32_bf16(a1, b3, acc[1][3], 0, 0, 0);
            acc[2][3] = __builtin_amdgcn_mfma_f32_16x16x32_bf16(a2, b3, acc[2][3], 0, 0, 0);
        }

        float* yb = Y + (pair0 + (long)chunk * Gp) * 768;
        #pragma unroll
        for (int mi = 0; mi < 3; ++mi) {
            #pragma unroll
            for (int r = 0; r < 4; ++r) {
                const int m = mi * 16 + lq * 4 + r;   // 0..47
                const int p = m / 3;
                const int i = m - p * 3;
                const int rowoff = p * 768 + i;
                #pragma unroll
                for (int ni = 0; ni < 4; ++ni) {
                    const int f = (4 * wc + ni) * 16 + lr;
                    yb[rowoff + f * 3] = acc[mi][ni][r];
                }
            }
        }
    };

    // ---------------- pipeline ----------------
    if (w < 4) PRODUCE(0);
    __syncthreads();

    for (int t = 0; t < NCH; ++t) {
        if (w < 4) {
            if (t + 1 < NCH) PRODUCE(t + 1);
        } else {
            CONSUME(t);
        }
        __syncthreads();
    }
}

extern "C" void kernel_launch(void* const* d_in, const int* in_sizes, int n_in,
                              void* d_out, int out_size, void* d_ws, size_t ws_size,
                              hipStream_t stream) {
    const float* X  = (const float*)d_in[0];
    const float* J  = (const float*)d_in[1];
    const float* A  = (const float*)d_in[2];
    const float* B  = (const float*)d_in[3];
    const float* Cm = (const float*)d_in[4];
    float* Y = (float*)d_out;
    bf16_t* W = (bf16_t*)d_ws;    // 393,216 B

    convert_w_kernel<<<192, 256, 0, stream>>>(A, B, Cm, W);

    const int nbn = in_sizes[1] / (Dd * 4);       // 32768
    const int blocks = nbn / (Gp * NCH);          // 256
    alaq_pc_kernel<<<blocks, TPB, 0, stream>>>(X, J, W, Y);
}

// Round 13
// 145.379 us; speedup vs baseline: 2.2185x; 2.2185x over previous
//
#include <hip/hip_runtime.h>

// Affine_Linear_Abla_Quat — v9 = v3 + inline-asm phase-1 load staging.
// Learned: compiler re-sinks C++ load batching to VGPR~52 (v3/v4/v7), so only
// ~4 loads/wave in flight -> 0.7 TB/s (Little's law). asm volatile loads pin
// all 24 loads/thread in flight (~7KB/CU) -> phase 1 becomes BW-bound.
// Everything else identical to v3 (144us champion): Gp=16, TPB=512, LDS 73.7KB,
// LB(512,4) 2 blocks/CU, XOR-swizzled TT, full-unroll k-loop, W from L2.

typedef __bf16 bf16_t;
typedef __attribute__((ext_vector_type(8))) __bf16 bf16x8;
typedef __attribute__((ext_vector_type(4))) __bf16 bf16x4;
typedef __attribute__((ext_vector_type(4))) float f32x4;
typedef __attribute__((ext_vector_type(2))) float f32x2;

constexpr int Dd  = 256;   // D == F
constexpr int Gp  = 16;    // pairs per block -> M = 48
constexpr int TPB = 512;   // 8 waves

__device__ __forceinline__ bf16_t to_bf16(float f) {
    unsigned u = __builtin_bit_cast(unsigned, f);
    u += 0x7FFFu + ((u >> 16) & 1u);          // RNE
    unsigned short h = (unsigned short)(u >> 16);
    return __builtin_bit_cast(bf16_t, h);
}

// swizzled element index into TT: row-major [48][768], 16B granule XOR (row&7)
__device__ __forceinline__ int swz(int row, int k) {
    return row * 768 + (k ^ ((row & 7) << 3));
}

// ---- prologue: A,B,C (f32 256x256) -> W bf16 [3][256][256] in d_ws ----
__global__ __launch_bounds__(256)
void convert_w_kernel(const float* __restrict__ A, const float* __restrict__ B,
                      const float* __restrict__ C, bf16_t* __restrict__ W)
{
    const int e4 = (blockIdx.x * 256 + threadIdx.x) * 4;
    const float* src;
    if (e4 < 65536)        src = A + e4;
    else if (e4 < 131072)  src = B + (e4 - 65536);
    else                   src = C + (e4 - 131072);
    const float4 v = *reinterpret_cast<const float4*>(src);
    bf16x4 o;
    o[0] = to_bf16(v.x); o[1] = to_bf16(v.y); o[2] = to_bf16(v.z); o[3] = to_bf16(v.w);
    *reinterpret_cast<bf16x4*>(W + e4) = o;
}

// ------------------------------ main kernel ------------------------------
__global__ __launch_bounds__(TPB, 4)
void alaq_mfma_kernel(const float* __restrict__ X, const float* __restrict__ J,
                      const bf16_t* __restrict__ W, float* __restrict__ Y)
{
    __shared__ bf16_t TT[48 * 768];   // 73,728 B -> 2 blocks/CU

    const int tid = threadIdx.x;
    const long bn0 = (long)blockIdx.x * Gp;
    const long ebase = bn0 * Dd;

    // ---------------- Phase 1: asm-pinned loads, then compute ----------------
    f32x4 jv[8];
    f32x2 xab[8];
    float xc[8];
    #pragma unroll
    for (int rr = 0; rr < 8; ++rr) {
        const long base = ebase + rr * TPB + tid;
        const float* jp = J + base * 4;
        const float* xp = X + base * 3;
        asm volatile("global_load_dwordx4 %0, %1, off"
                     : "=v"(jv[rr]) : "v"(jp) : "memory");
        asm volatile("global_load_dwordx2 %0, %1, off"
                     : "=v"(xab[rr]) : "v"(xp) : "memory");
        asm volatile("global_load_dword %0, %1, off offset:8"
                     : "=v"(xc[rr]) : "v"(xp) : "memory");
    }
    asm volatile("s_waitcnt vmcnt(0)" ::: "memory");
    __builtin_amdgcn_sched_barrier(0);

    #pragma unroll
    for (int rr = 0; rr < 8; ++rr) {
        const int idx = rr * TPB + tid;
        const int p = idx >> 8;
        const int e = idx & 255;

        const float qxr = jv[rr][0], qyr = jv[rr][1], qzr = jv[rr][2], qwr = jv[rr][3];
        const float x0 = xab[rr][0], x1 = xab[rr][1], x2 = xc[rr];

        const float nsq = qxr*qxr + qyr*qyr + qzr*qzr + qwr*qwr;
        const float inv = 1.0f / fmaxf(sqrtf(nsq), 1e-12f);
        const float qx = qxr*inv, qy = qyr*inv, qz = qzr*inv, qw = qwr*inv;
        const float s = 2.0f / (qw*qw + qx*qx + qy*qy + qz*qz);

        const float r00 = 1.0f - s*(qy*qy + qz*qz);
        const float r01 = s*(qx*qy - qz*qw);
        const float r02 = s*(qx*qz + qy*qw);
        const float r10 = s*(qx*qy + qz*qw);
        const float r11 = 1.0f - s*(qx*qx + qz*qz);
        const float r12 = s*(qy*qz - qx*qw);
        const float r20 = s*(qx*qz - qy*qw);
        const float r21 = s*(qy*qz + qx*qw);
        const float r22 = 1.0f - s*(qx*qx + qy*qy);

        const float rt0 = r00*x0 + r10*x1 + r20*x2;
        const float rt1 = r01*x0 + r11*x1 + r21*x2;
        const float rt2 = r02*x0 + r12*x1 + r22*x2;

        const int row = p * 3;
        TT[swz(row    ,       e)] = to_bf16(r00*rt0 + r01*rt1);
        TT[swz(row + 1,       e)] = to_bf16(r10*rt0 + r11*rt1);
        TT[swz(row + 2,       e)] = to_bf16(r20*rt0 + r21*rt1);
        TT[swz(row    , 256 + e)] = to_bf16(r01*rt0 - r00*rt1);
        TT[swz(row + 1, 256 + e)] = to_bf16(r11*rt0 - r10*rt1);
        TT[swz(row + 2, 256 + e)] = to_bf16(r21*rt0 - r20*rt1);
        TT[swz(row    , 512 + e)] = to_bf16(r02*rt2);
        TT[swz(row + 1, 512 + e)] = to_bf16(r12*rt2);
        TT[swz(row + 2, 512 + e)] = to_bf16(r22*rt2);
    }
    __syncthreads();

    // ---------------- Phase 2: MFMA GEMM (v3 form, untouched) ----------------
    const int w  = tid >> 6;          // wave 0..7, owns f-strips {2w, 2w+1}
    const int l  = tid & 63;
    const int lr = l & 15;
    const int lq = l >> 4;

    f32x4 acc[3][2] = {};

    const int f0 = (2 * w) * 16 + lr;
    const bf16_t* Wf0 = W + f0 * 256 + (lq << 3);
    const bf16_t* Wf1 = Wf0 + 16 * 256;
    const int swzmask = (lr & 7) << 3;

    #pragma unroll
    for (int k0 = 0; k0 < 24; ++k0) {
        const int term = k0 >> 3;
        const int eb   = (k0 & 7) << 5;
        const bf16x8 b0 = *reinterpret_cast<const bf16x8*>(Wf0 + (term << 16) + eb);
        const bf16x8 b1 = *reinterpret_cast<const bf16x8*>(Wf1 + (term << 16) + eb);

        const int kswz = (((k0 << 5) + (lq << 3)) ^ swzmask);
        const bf16x8 a0 = *reinterpret_cast<const bf16x8*>(&TT[      lr  * 768 + kswz]);
        const bf16x8 a1 = *reinterpret_cast<const bf16x8*>(&TT[(16 + lr) * 768 + kswz]);
        const bf16x8 a2 = *reinterpret_cast<const bf16x8*>(&TT[(32 + lr) * 768 + kswz]);

        acc[0][0] = __builtin_amdgcn_mfma_f32_16x16x32_bf16(a0, b0, acc[0][0], 0, 0, 0);
        acc[1][0] = __builtin_amdgcn_mfma_f32_16x16x32_bf16(a1, b0, acc[1][0], 0, 0, 0);
        acc[2][0] = __builtin_amdgcn_mfma_f32_16x16x32_bf16(a2, b0, acc[2][0], 0, 0, 0);
        acc[0][1] = __builtin_amdgcn_mfma_f32_16x16x32_bf16(a0, b1, acc[0][1], 0, 0, 0);
        acc[1][1] = __builtin_amdgcn_mfma_f32_16x16x32_bf16(a1, b1, acc[1][1], 0, 0, 0);
        acc[2][1] = __builtin_amdgcn_mfma_f32_16x16x32_bf16(a2, b1, acc[2][1], 0, 0, 0);
    }

    // ---------------- Epilogue ----------------
    #pragma unroll
    for (int mi = 0; mi < 3; ++mi) {
        #pragma unroll
        for (int ni = 0; ni < 2; ++ni) {
            const int f = (2 * w + ni) * 16 + lr;
            #pragma unroll
            for (int r = 0; r < 4; ++r) {
                const int m = mi * 16 + lq * 4 + r;
                const int p = m / 3;
                const int i = m - p * 3;
                Y[(bn0 + p) * 768 + f * 3 + i] = acc[mi][ni][r];
            }
        }
    }
}

extern "C" void kernel_launch(void* const* d_in, const int* in_sizes, int n_in,
                              void* d_out, int out_size, void* d_ws, size_t ws_size,
                              hipStream_t stream) {
    const float* X  = (const float*)d_in[0];
    const float* J  = (const float*)d_in[1];
    const float* A  = (const float*)d_in[2];
    const float* B  = (const float*)d_in[3];
    const float* Cm = (const float*)d_in[4];
    float* Y = (float*)d_out;
    bf16_t* W = (bf16_t*)d_ws;    // 393,216 B

    convert_w_kernel<<<192, 256, 0, stream>>>(A, B, Cm, W);

    const int nbn = in_sizes[1] / (Dd * 4);       // 32768
    const int blocks = nbn / Gp;                  // 2048
    alaq_mfma_kernel<<<blocks, TPB, 0, stream>>>(X, J, W, Y);
}